// Round 1
// baseline (10346.330 us; speedup 1.0000x reference)
//
#include <hip/hip_runtime.h>

typedef unsigned int u32_t;
typedef unsigned int u32x4 __attribute__((ext_vector_type(4)));

#define S_LEN 2048
#define EDIM  1024
#define HDIM  1024
#define GDIM  4096   // 4*H

#define POISON 0xAAAAAAAAu

// ---------------------------------------------------------------------------
// Phase A: ix[t][r] = emb[tokens[t]] . W_ih[r] + b_ih[r] + b_hh[r]
// fp32 LDS-tiled GEMM, 64x64 tile, BK=16, 256 threads, 4x4 micro-tile. ~92us.
// (unchanged)
// ---------------------------------------------------------------------------
__global__ __launch_bounds__(256)
void ix_gemm(const int* __restrict__ tokens, const float* __restrict__ emb,
             const float* __restrict__ Wih, const float* __restrict__ bih,
             const float* __restrict__ bhh, float* __restrict__ ix)
{
    __shared__ float As[16][68];
    __shared__ float Bs[16][68];
    const int t0  = blockIdx.x * 64;
    const int r0  = blockIdx.y * 64;
    const int tid = threadIdx.x;
    const int tx  = tid & 15;          // n-direction
    const int ty  = tid >> 4;          // m-direction
    const int m_a = tid & 63;          // staging row
    const int k_a = (tid >> 6) << 2;   // staging k offset: 0,4,8,12

    const float* arow = emb + (size_t)tokens[t0 + m_a] * EDIM + k_a;
    const float* brow = Wih + (size_t)(r0 + m_a) * EDIM + k_a;

    float acc[4][4] = {};
    for (int kk = 0; kk < EDIM; kk += 16) {
        float4 av = *(const float4*)(arow + kk);
        float4 bv = *(const float4*)(brow + kk);
        __syncthreads();
        As[k_a + 0][m_a] = av.x; As[k_a + 1][m_a] = av.y;
        As[k_a + 2][m_a] = av.z; As[k_a + 3][m_a] = av.w;
        Bs[k_a + 0][m_a] = bv.x; Bs[k_a + 1][m_a] = bv.y;
        Bs[k_a + 2][m_a] = bv.z; Bs[k_a + 3][m_a] = bv.w;
        __syncthreads();
#pragma unroll
        for (int k = 0; k < 16; ++k) {
            float4 a = *(const float4*)&As[k][ty << 2];
            float4 b = *(const float4*)&Bs[k][tx << 2];
            acc[0][0] += a.x * b.x; acc[0][1] += a.x * b.y;
            acc[0][2] += a.x * b.z; acc[0][3] += a.x * b.w;
            acc[1][0] += a.y * b.x; acc[1][1] += a.y * b.y;
            acc[1][2] += a.y * b.z; acc[1][3] += a.y * b.w;
            acc[2][0] += a.z * b.x; acc[2][1] += a.z * b.y;
            acc[2][2] += a.z * b.z; acc[2][3] += a.z * b.w;
            acc[3][0] += a.w * b.x; acc[3][1] += a.w * b.y;
            acc[3][2] += a.w * b.z; acc[3][3] += a.w * b.w;
        }
    }
    const int n0 = r0 + (tx << 2);
    float b0 = bih[n0 + 0] + bhh[n0 + 0];
    float b1 = bih[n0 + 1] + bhh[n0 + 1];
    float b2 = bih[n0 + 2] + bhh[n0 + 2];
    float b3 = bih[n0 + 3] + bhh[n0 + 3];
#pragma unroll
    for (int i = 0; i < 4; ++i) {
        int m = t0 + (ty << 2) + i;
        float4 v = make_float4(acc[i][0] + b0, acc[i][1] + b1,
                               acc[i][2] + b2, acc[i][3] + b3);
        *(float4*)(ix + (size_t)m * GDIM + n0) = v;
    }
}

// ---------------------------------------------------------------------------
// Phase B: persistent recurrence. 256 blocks x 256 threads = 1 block/CU,
// 4 waves. Wave w computes gate rows {j, H+j, 2H+j, 3H+j}, j = 4*block + w.
// Weights in LDS (64 KB staged once), conflict-free ds_read_b128.
//
// NEW vs prev round: the consumer poll is ONE 16B cache-bypassing
// global_load_dwordx4 (sc0 sc1 = agent-coherent, bypass L1+L2) per thread
// per round, replacing 4 independent 4B agent atomic loads. Rationale:
// the step time (6580 cy) was dominated by poll-storm queueing at the
// coherence point -- 262K 4B requests/round against 64 hot lines
// saturates the L3 slices (service-rate equilibrium ~4096 cy/round).
// 1 request/thread/round cuts that 4x. Per-dword atomicity of dwordx4
// + single write per location per run makes sticky-merge unnecessary:
// retry the whole 16B until all 4 dwords are non-poison.
// ---------------------------------------------------------------------------
__device__ __forceinline__ float fast_sigmoid(float x) {
    return 1.0f / (1.0f + __expf(-x));
}
__device__ __forceinline__ float fast_tanh(float x) {
    return 1.0f - 2.0f / (__expf(2.0f * x) + 1.0f);
}

// Agent-coherent synchronous 16B load: bypasses L1 (sc0) and L2 (sc1) so it
// observes remote-XCD stores at the coherence point. waitcnt inside the asm
// makes the result valid at exit; the "=v" dataflow orders consumers.
__device__ __forceinline__ u32x4 cohload16(const u32_t* p) {
    u32x4 v;
    unsigned long long a = (unsigned long long)p;
    asm volatile("global_load_dwordx4 %0, %1, off sc0 sc1\n\t"
                 "s_waitcnt vmcnt(0)"
                 : "=v"(v) : "v"(a) : "memory");
    return v;
}

__global__ __launch_bounds__(256)
void lstm_rec(const float* __restrict__ Whh,   // [4H, H]
              const float* __restrict__ ix,    // [S, 4H]
              u32_t* hslot,                    // [S][H] poison-init
              float* __restrict__ out)         // [H]
{
    const int tid  = threadIdx.x;
    const int wid  = tid >> 6;                 // 0..3
    const int lane = tid & 63;
    const int b    = blockIdx.x;
    const int j    = b * 4 + wid;              // 0..1023

    __shared__ float wlds[4][4][HDIM];         // 64 KB: [wave][gate][k]
    __shared__ float hs[2][HDIM];              // 8 KB, double-buffered

    // Stage weights once: 16 rows x 4KB, float4-coalesced.
#pragma unroll
    for (int w = 0; w < 4; ++w)
#pragma unroll
        for (int g = 0; g < 4; ++g) {
            const float* row = Whh + (size_t)(g * HDIM + b * 4 + w) * HDIM;
            *(float4*)&wlds[w][g][tid << 2] = *(const float4*)(row + (tid << 2));
        }
    __syncthreads();

    float c = 0.0f;
    u32x4 pv;
    pv[0] = POISON; pv[1] = POISON; pv[2] = POISON; pv[3] = POISON;

    for (int t = 0; t < S_LEN; ++t) {
        // ix contributions (wave-uniform); issued early, consumed post-reduce.
        const float* ixt = ix + (size_t)t * GDIM;
        float bi = ixt[j];
        float bf = ixt[HDIM + j];
        float bg = ixt[2 * HDIM + j];
        float bo = ixt[3 * HDIM + j];

        const int buf = t & 1;
        if (t == 0) {
            *(float4*)&hs[0][tid << 2] = make_float4(0.f, 0.f, 0.f, 0.f);
        } else {
            const u32_t* src = hslot + (size_t)(t - 1) * HDIM + (tid << 2);
            // pv holds the speculative prefetch from the bottom of step t-1.
            while ((pv[0] == POISON) | (pv[1] == POISON) |
                   (pv[2] == POISON) | (pv[3] == POISON)) {
                __builtin_amdgcn_s_sleep(1);   // damp fabric poll storm
                pv = cohload16(src);
            }
            *(float4*)&hs[buf][tid << 2] =
                make_float4(__uint_as_float(pv[0]), __uint_as_float(pv[1]),
                            __uint_as_float(pv[2]), __uint_as_float(pv[3]));
        }
        __syncthreads();   // single barrier/step (hs double-buffered)

        // 4 gates x 16 k-elements per lane; weights + h via ds_read_b128.
        float4 h0 = *(const float4*)&hs[buf][0 * 256 + (lane << 2)];
        float4 h1 = *(const float4*)&hs[buf][1 * 256 + (lane << 2)];
        float4 h2 = *(const float4*)&hs[buf][2 * 256 + (lane << 2)];
        float4 h3 = *(const float4*)&hs[buf][3 * 256 + (lane << 2)];

        float s[4];
#pragma unroll
        for (int g = 0; g < 4; ++g) {
            float4 w0 = *(const float4*)&wlds[wid][g][0 * 256 + (lane << 2)];
            float4 w1 = *(const float4*)&wlds[wid][g][1 * 256 + (lane << 2)];
            float4 w2 = *(const float4*)&wlds[wid][g][2 * 256 + (lane << 2)];
            float4 w3 = *(const float4*)&wlds[wid][g][3 * 256 + (lane << 2)];
            s[g] = w0.x*h0.x + w0.y*h0.y + w0.z*h0.z + w0.w*h0.w
                 + w1.x*h1.x + w1.y*h1.y + w1.z*h1.z + w1.w*h1.w
                 + w2.x*h2.x + w2.y*h2.y + w2.z*h2.z + w2.w*h2.w
                 + w3.x*h3.x + w3.y*h3.y + w3.z*h3.z + w3.w*h3.w;
        }

        // 64-lane butterfly all-reduce, 4 interleaved chains.
#pragma unroll
        for (int sh = 32; sh > 0; sh >>= 1) {
            s[0] += __shfl_xor(s[0], sh, 64);
            s[1] += __shfl_xor(s[1], sh, 64);
            s[2] += __shfl_xor(s[2], sh, 64);
            s[3] += __shfl_xor(s[3], sh, 64);
        }

        float si = s[0] + bi, sf = s[1] + bf, sg = s[2] + bg, so = s[3] + bo;
        float ig = fast_sigmoid(si);
        float fg = fast_sigmoid(sf);
        float og = fast_sigmoid(so);
        float gt = fast_tanh(sg);
        c = fg * c + ig * gt;                  // redundant across lanes (consistent)
        float h = og * fast_tanh(c);

        if (lane == 0) {
            u32_t hb = __float_as_uint(h);
            if (hb == POISON) hb = 0u;         // hang-proof canonicalization
            __hip_atomic_store(hslot + (size_t)t * HDIM + j, hb,
                               __ATOMIC_RELAXED, __HIP_MEMORY_SCOPE_AGENT);
            if (t == S_LEN - 1) out[j] = h;
        }

        // Speculative prefetch of next step's 16B packet; if any dword is
        // still poison the poll loop at the top of t+1 re-reads the full 16B.
        pv = cohload16(hslot + (size_t)t * HDIM + (tid << 2));
    }
}

// ---------------------------------------------------------------------------
extern "C" void kernel_launch(void* const* d_in, const int* in_sizes, int n_in,
                              void* d_out, int out_size, void* d_ws, size_t ws_size,
                              hipStream_t stream) {
    const int*   tokens = (const int*)  d_in[0];
    const float* emb    = (const float*)d_in[1];
    const float* Wih    = (const float*)d_in[2];
    const float* Whh    = (const float*)d_in[3];
    const float* bih    = (const float*)d_in[4];
    const float* bhh    = (const float*)d_in[5];
    float* out = (float*)d_out;

    float* ix    = (float*)d_ws;                                     // 33.55 MB
    u32_t* hslot = (u32_t*)((char*)d_ws + (size_t)S_LEN * GDIM * 4); // 8 MB
    // total ws use: 41.9 MB

    dim3 gA(S_LEN / 64, GDIM / 64);
    hipLaunchKernelGGL(ix_gemm, gA, dim3(256), 0, stream,
                       tokens, emb, Wih, bih, bhh, ix);
    hipLaunchKernelGGL(lstm_rec, dim3(256), dim3(256), 0, stream,
                       Whh, ix, hslot, out);
}

// Round 2
// 7552.631 us; speedup vs baseline: 1.3699x; 1.3699x over previous
//
#include <hip/hip_runtime.h>

typedef unsigned int u32_t;
typedef unsigned int u32x4 __attribute__((ext_vector_type(4)));

#define S_LEN 2048
#define EDIM  1024
#define HDIM  1024
#define GDIM  4096   // 4*H

#define POISON 0xAAAAAAAAu

// ---------------------------------------------------------------------------
// Phase A: ix[t][r] = emb[tokens[t]] . W_ih[r] + b_ih[r] + b_hh[r]
// fp32 LDS-tiled GEMM, 64x64 tile, BK=16, 256 threads, 4x4 micro-tile. ~92us.
// (unchanged)
// ---------------------------------------------------------------------------
__global__ __launch_bounds__(256)
void ix_gemm(const int* __restrict__ tokens, const float* __restrict__ emb,
             const float* __restrict__ Wih, const float* __restrict__ bih,
             const float* __restrict__ bhh, float* __restrict__ ix)
{
    __shared__ float As[16][68];
    __shared__ float Bs[16][68];
    const int t0  = blockIdx.x * 64;
    const int r0  = blockIdx.y * 64;
    const int tid = threadIdx.x;
    const int tx  = tid & 15;          // n-direction
    const int ty  = tid >> 4;          // m-direction
    const int m_a = tid & 63;          // staging row
    const int k_a = (tid >> 6) << 2;   // staging k offset: 0,4,8,12

    const float* arow = emb + (size_t)tokens[t0 + m_a] * EDIM + k_a;
    const float* brow = Wih + (size_t)(r0 + m_a) * EDIM + k_a;

    float acc[4][4] = {};
    for (int kk = 0; kk < EDIM; kk += 16) {
        float4 av = *(const float4*)(arow + kk);
        float4 bv = *(const float4*)(brow + kk);
        __syncthreads();
        As[k_a + 0][m_a] = av.x; As[k_a + 1][m_a] = av.y;
        As[k_a + 2][m_a] = av.z; As[k_a + 3][m_a] = av.w;
        Bs[k_a + 0][m_a] = bv.x; Bs[k_a + 1][m_a] = bv.y;
        Bs[k_a + 2][m_a] = bv.z; Bs[k_a + 3][m_a] = bv.w;
        __syncthreads();
#pragma unroll
        for (int k = 0; k < 16; ++k) {
            float4 a = *(const float4*)&As[k][ty << 2];
            float4 b = *(const float4*)&Bs[k][tx << 2];
            acc[0][0] += a.x * b.x; acc[0][1] += a.x * b.y;
            acc[0][2] += a.x * b.z; acc[0][3] += a.x * b.w;
            acc[1][0] += a.y * b.x; acc[1][1] += a.y * b.y;
            acc[1][2] += a.y * b.z; acc[1][3] += a.y * b.w;
            acc[2][0] += a.z * b.x; acc[2][1] += a.z * b.y;
            acc[2][2] += a.z * b.z; acc[2][3] += a.z * b.w;
            acc[3][0] += a.w * b.x; acc[3][1] += a.w * b.y;
            acc[3][2] += a.w * b.z; acc[3][3] += a.w * b.w;
        }
    }
    const int n0 = r0 + (tx << 2);
    float b0 = bih[n0 + 0] + bhh[n0 + 0];
    float b1 = bih[n0 + 1] + bhh[n0 + 1];
    float b2 = bih[n0 + 2] + bhh[n0 + 2];
    float b3 = bih[n0 + 3] + bhh[n0 + 3];
#pragma unroll
    for (int i = 0; i < 4; ++i) {
        int m = t0 + (ty << 2) + i;
        float4 v = make_float4(acc[i][0] + b0, acc[i][1] + b1,
                               acc[i][2] + b2, acc[i][3] + b3);
        *(float4*)(ix + (size_t)m * GDIM + n0) = v;
    }
}

// ---------------------------------------------------------------------------
// Phase B: persistent recurrence. 256 blocks x 256 threads = 1 block/CU,
// 4 waves. Wave w computes gate rows {j, H+j, 2H+j, 3H+j}, j = 4*block + w.
// Weights in LDS (64 KB staged once), conflict-free ds_read_b128.
//
// R1: poll is ONE 16B load at AGENT scope (sc1 only -- coherent at L3/MALL,
// same coherence point as the proven __hip_atomic_load(AGENT) baseline).
// R0's sc0+sc1 was SYSTEM scope: every poll went past L3 toward HBM
// (FETCH_SIZE 2x, +77% time). Also: no s_sleep (the synchronous load
// self-throttles at one request per round trip), and next-step ix loads
// are issued BEFORE the bottom-of-loop prefetch so their L2 latency hides
// under its vmcnt(0) wait.
// ---------------------------------------------------------------------------
__device__ __forceinline__ float fast_sigmoid(float x) {
    return 1.0f / (1.0f + __expf(-x));
}
__device__ __forceinline__ float fast_tanh(float x) {
    return 1.0f - 2.0f / (__expf(2.0f * x) + 1.0f);
}

// Agent-coherent synchronous 16B load: sc1 bypasses the (non-coherent) L2
// so it observes remote-XCD stores at the L3 coherence point, without
// forcing an HBM round trip. waitcnt inside the asm makes the result valid
// at exit; the "=v" dataflow orders consumers (single asm block, so the
// rule-18 hoist hazard does not apply).
__device__ __forceinline__ u32x4 cohload16(const u32_t* p) {
    u32x4 v;
    asm volatile("global_load_dwordx4 %0, %1, off sc1\n\t"
                 "s_waitcnt vmcnt(0)"
                 : "=v"(v) : "v"((unsigned long long)p) : "memory");
    return v;
}

__global__ __launch_bounds__(256)
void lstm_rec(const float* __restrict__ Whh,   // [4H, H]
              const float* __restrict__ ix,    // [S, 4H]
              u32_t* hslot,                    // [S][H] poison-init
              float* __restrict__ out)         // [H]
{
    const int tid  = threadIdx.x;
    const int wid  = tid >> 6;                 // 0..3
    const int lane = tid & 63;
    const int b    = blockIdx.x;
    const int j    = b * 4 + wid;              // 0..1023

    __shared__ float wlds[4][4][HDIM];         // 64 KB: [wave][gate][k]
    __shared__ float hs[2][HDIM];              // 8 KB, double-buffered

    // Stage weights once: 16 rows x 4KB, float4-coalesced.
#pragma unroll
    for (int w = 0; w < 4; ++w)
#pragma unroll
        for (int g = 0; g < 4; ++g) {
            const float* row = Whh + (size_t)(g * HDIM + b * 4 + w) * HDIM;
            *(float4*)&wlds[w][g][tid << 2] = *(const float4*)(row + (tid << 2));
        }
    __syncthreads();

    float c = 0.0f;
    u32x4 pv;
    pv[0] = POISON; pv[1] = POISON; pv[2] = POISON; pv[3] = POISON;

    // Software-pipelined ix contributions: loaded one step ahead so the
    // L2 latency hides under the bottom-of-loop prefetch wait.
    float bi = ix[j];
    float bf = ix[HDIM + j];
    float bg = ix[2 * HDIM + j];
    float bo = ix[3 * HDIM + j];

    for (int t = 0; t < S_LEN; ++t) {
        const int buf = t & 1;
        if (t == 0) {
            *(float4*)&hs[0][tid << 2] = make_float4(0.f, 0.f, 0.f, 0.f);
        } else {
            const u32_t* src = hslot + (size_t)(t - 1) * HDIM + (tid << 2);
            // pv holds the speculative prefetch from the bottom of step t-1.
            // Each dword is written exactly once (poison-canonicalized), and
            // dwordx4 is per-dword atomic, so whole-packet retry is race-free.
            while ((pv[0] == POISON) | (pv[1] == POISON) |
                   (pv[2] == POISON) | (pv[3] == POISON)) {
                pv = cohload16(src);   // self-throttled: one req per round trip
            }
            *(float4*)&hs[buf][tid << 2] =
                make_float4(__uint_as_float(pv[0]), __uint_as_float(pv[1]),
                            __uint_as_float(pv[2]), __uint_as_float(pv[3]));
        }
        __syncthreads();   // single barrier/step (hs double-buffered)

        // 4 gates x 16 k-elements per lane; weights + h via ds_read_b128.
        float4 h0 = *(const float4*)&hs[buf][0 * 256 + (lane << 2)];
        float4 h1 = *(const float4*)&hs[buf][1 * 256 + (lane << 2)];
        float4 h2 = *(const float4*)&hs[buf][2 * 256 + (lane << 2)];
        float4 h3 = *(const float4*)&hs[buf][3 * 256 + (lane << 2)];

        float s[4];
#pragma unroll
        for (int g = 0; g < 4; ++g) {
            float4 w0 = *(const float4*)&wlds[wid][g][0 * 256 + (lane << 2)];
            float4 w1 = *(const float4*)&wlds[wid][g][1 * 256 + (lane << 2)];
            float4 w2 = *(const float4*)&wlds[wid][g][2 * 256 + (lane << 2)];
            float4 w3 = *(const float4*)&wlds[wid][g][3 * 256 + (lane << 2)];
            s[g] = w0.x*h0.x + w0.y*h0.y + w0.z*h0.z + w0.w*h0.w
                 + w1.x*h1.x + w1.y*h1.y + w1.z*h1.z + w1.w*h1.w
                 + w2.x*h2.x + w2.y*h2.y + w2.z*h2.z + w2.w*h2.w
                 + w3.x*h3.x + w3.y*h3.y + w3.z*h3.z + w3.w*h3.w;
        }

        // 64-lane butterfly all-reduce, 4 interleaved chains.
#pragma unroll
        for (int sh = 32; sh > 0; sh >>= 1) {
            s[0] += __shfl_xor(s[0], sh, 64);
            s[1] += __shfl_xor(s[1], sh, 64);
            s[2] += __shfl_xor(s[2], sh, 64);
            s[3] += __shfl_xor(s[3], sh, 64);
        }

        float si = s[0] + bi, sf = s[1] + bf, sg = s[2] + bg, so = s[3] + bo;
        float ig = fast_sigmoid(si);
        float fg = fast_sigmoid(sf);
        float og = fast_sigmoid(so);
        float gt = fast_tanh(sg);
        c = fg * c + ig * gt;                  // redundant across lanes (consistent)
        float h = og * fast_tanh(c);

        if (lane == 0) {
            u32_t hb = __float_as_uint(h);
            if (hb == POISON) hb = 0u;         // hang-proof canonicalization
            __hip_atomic_store(hslot + (size_t)t * HDIM + j, hb,
                               __ATOMIC_RELAXED, __HIP_MEMORY_SCOPE_AGENT);
            if (t == S_LEN - 1) out[j] = h;
        }

        // Issue next step's ix loads BEFORE the synchronous prefetch so
        // their latency hides under its vmcnt(0) wait.
        if (t + 1 < S_LEN) {
            const float* nxt = ix + (size_t)(t + 1) * GDIM;
            bi = nxt[j];
            bf = nxt[HDIM + j];
            bg = nxt[2 * HDIM + j];
            bo = nxt[3 * HDIM + j];
        }

        // Speculative prefetch of next step's 16B packet; stragglers are
        // re-polled at the top of the next iteration.
        pv = cohload16(hslot + (size_t)t * HDIM + (tid << 2));
    }
}

// ---------------------------------------------------------------------------
extern "C" void kernel_launch(void* const* d_in, const int* in_sizes, int n_in,
                              void* d_out, int out_size, void* d_ws, size_t ws_size,
                              hipStream_t stream) {
    const int*   tokens = (const int*)  d_in[0];
    const float* emb    = (const float*)d_in[1];
    const float* Wih    = (const float*)d_in[2];
    const float* Whh    = (const float*)d_in[3];
    const float* bih    = (const float*)d_in[4];
    const float* bhh    = (const float*)d_in[5];
    float* out = (float*)d_out;

    float* ix    = (float*)d_ws;                                     // 33.55 MB
    u32_t* hslot = (u32_t*)((char*)d_ws + (size_t)S_LEN * GDIM * 4); // 8 MB
    // total ws use: 41.9 MB

    dim3 gA(S_LEN / 64, GDIM / 64);
    hipLaunchKernelGGL(ix_gemm, gA, dim3(256), 0, stream,
                       tokens, emb, Wih, bih, bhh, ix);
    hipLaunchKernelGGL(lstm_rec, dim3(256), dim3(256), 0, stream,
                       Whh, ix, hslot, out);
}